// Round 13
// baseline (4498.680 us; speedup 1.0000x reference)
//
#include <hip/hip_runtime.h>
#include <hip/hip_bf16.h>

#define B_  64
#define TX  128
#define H_  1024
#define E_  512
#define KY  32000
#define H2  2048   // 2H
#define H3  3072   // 3H
#define EC  2560   // E+2H
#define M_  (TX*B_) // 8192
#define WST 132    // LDS row stride for f32 W tile (gemmT)
#define NS  4      // K-splits for lsm GEMM (KC=768)
// DIAGNOSTIC repeat factors (remove next round). Each probed kernel's body is
// idempotent (reads/writes disjoint), so reps give identical output.
#define REP_K1  24
#define REP_KC  24
#define REP_K4  32
#define REP_KG  24
#define REP_K7  32

typedef __bf16 bf16x8 __attribute__((ext_vector_type(8)));
typedef unsigned short u16x8 __attribute__((ext_vector_type(8)));
typedef float f32x4 __attribute__((ext_vector_type(4)));

// f32 -> bf16 round-to-nearest-even
__device__ __forceinline__ unsigned short f2bf(float f) {
  unsigned int u = __builtin_bit_cast(unsigned int, f);
  u += 0x7fff + ((u >> 16) & 1);
  return (unsigned short)(u >> 16);
}

// async global->LDS, 16B per lane
__device__ __forceinline__ void gload16(const void* g, void* l) {
  __builtin_amdgcn_global_load_lds(
      (const __attribute__((address_space(1))) unsigned int*)g,
      (__attribute__((address_space(3))) unsigned int*)l, 16, 0, 0);
}

// ---------------- merged convert (+REP probe) ----------------
__global__ void kc_all(const float* __restrict__ enc, const float* __restrict__ aW1,
                       unsigned short* __restrict__ encb, unsigned short* __restrict__ w1b) {
  size_t gid = (size_t)blockIdx.x * 256 + threadIdx.x;
  for (int rep = 0; rep < REP_KC; ++rep) {
    if (gid < 2097152) {
      size_t i = gid * 8;
      float4 v0 = *(const float4*)(enc + i);
      float4 v1 = *(const float4*)(enc + i + 4);
      u16x8 o;
      o[0]=f2bf(v0.x); o[1]=f2bf(v0.y); o[2]=f2bf(v0.z); o[3]=f2bf(v0.w);
      o[4]=f2bf(v1.x); o[5]=f2bf(v1.y); o[6]=f2bf(v1.z); o[7]=f2bf(v1.w);
      *(u16x8*)(encb + i) = o;
    } else {
      size_t idx = (gid - 2097152) * 8;
      int row = (int)(idx >> 11);
      int col = (int)(idx & 2047);
      const float* s = aW1 + (size_t)row * H3 + H_ + col;
      float4 v0 = *(const float4*)(s);
      float4 v1 = *(const float4*)(s + 4);
      u16x8 o;
      o[0]=f2bf(v0.x); o[1]=f2bf(v0.y); o[2]=f2bf(v0.z); o[3]=f2bf(v0.w);
      o[4]=f2bf(v1.x); o[5]=f2bf(v1.y); o[6]=f2bf(v1.z); o[7]=f2bf(v1.w);
      *(u16x8*)(w1b + idx) = o;
    }
    __syncthreads();
  }
}

// ---------------- K1 (+REP probe) ----------------
__global__ void k1_hpart(const float* __restrict__ hidden, const float* __restrict__ aW1,
                         const float* __restrict__ ab1, float* __restrict__ hpart) {
  int b = blockIdx.y;
  int wave = threadIdx.x >> 6;
  int lane = threadIdx.x & 63;
  int h = blockIdx.x * 4 + wave;
  const float* wrow = aW1 + (size_t)h * H3;
  const float* hrow = hidden + b * H_;
  for (int rep = 0; rep < REP_K1; ++rep) {
    float acc = 0.f;
    for (int j = 0; j < H_ / 64; ++j) {
      int i = j * 64 + lane;
      acc += hrow[i] * wrow[i];
    }
    for (int off = 32; off; off >>= 1) acc += __shfl_down(acc, off);
    if (lane == 0) hpart[b * H_ + h] = acc + ab1[h];
    __syncthreads();
  }
}

// ---------------- K2 v3 (unchanged) ----------------
__global__ __launch_bounds__(256) void k2_mfma(
    const unsigned short* __restrict__ encb, const unsigned short* __restrict__ w1b,
    const float* __restrict__ hpart, const float* __restrict__ aW2,
    float* __restrict__ scorepart) {
  __shared__ __align__(16) unsigned short As[128 * 64];
  __shared__ __align__(16) unsigned short Bs[128 * 64];
  __shared__ float red[128][2];
  int wg = blockIdx.x;
  int swz = (wg & 7) * 64 + (wg >> 3);
  int mt = swz >> 3, nt = swz & 7;
  int m0 = mt * 128, n0 = nt * 128;
  int tid = threadIdx.x;
  int lane = tid & 63, wid = tid >> 6;
  int wr = wid >> 1, wc = wid & 1;
  f32x4 z = {0.f, 0.f, 0.f, 0.f};
  f32x4 acc[4][4];
  #pragma unroll
  for (int i = 0; i < 4; ++i)
    #pragma unroll
    for (int j = 0; j < 4; ++j) acc[i][j] = z;

  int srow = lane >> 3;
  int scol = ((lane & 7) ^ srow) * 8;
  for (int k0 = 0; k0 < H2; k0 += 64) {
    __syncthreads();
    #pragma unroll
    for (int i = 0; i < 4; ++i) {
      int ci = wid * 4 + i;
      int row = ci * 8 + srow;
      gload16(&encb[(size_t)(m0 + row) * H2 + k0 + scol], &As[ci * 512]);
      gload16(&w1b [(size_t)(n0 + row) * H2 + k0 + scol], &Bs[ci * 512]);
    }
    __syncthreads();
    #pragma unroll
    for (int ks = 0; ks < 2; ++ks) {
      bf16x8 af[4], bfr[4];
      #pragma unroll
      for (int i = 0; i < 4; ++i) {
        int ra = wr * 64 + i * 16 + (lane & 15);
        int rb = wc * 64 + i * 16 + (lane & 15);
        int og = (ks * 4 + (lane >> 4));
        af[i]  = *(const bf16x8*)&As[ra * 64 + ((og ^ (ra & 7)) * 8)];
        bfr[i] = *(const bf16x8*)&Bs[rb * 64 + ((og ^ (rb & 7)) * 8)];
      }
      #pragma unroll
      for (int mi = 0; mi < 4; ++mi)
        #pragma unroll
        for (int ni = 0; ni < 4; ++ni)
          acc[mi][ni] = __builtin_amdgcn_mfma_f32_16x16x32_bf16(af[mi], bfr[ni], acc[mi][ni], 0, 0, 0);
    }
  }
  int q = lane >> 4, c = lane & 15;
  #pragma unroll
  for (int mi = 0; mi < 4; ++mi) {
    #pragma unroll
    for (int r = 0; r < 4; ++r) {
      int mloc = wr * 64 + mi * 16 + q * 4 + r;
      int b = (mi * 16 + q * 4 + r) & 63;
      float p = 0.f;
      #pragma unroll
      for (int ni = 0; ni < 4; ++ni) {
        int n = n0 + wc * 64 + ni * 16 + c;
        p += aW2[n] * tanhf(hpart[b * H_ + n] + acc[mi][ni][r]);
      }
      p += __shfl_xor(p, 1); p += __shfl_xor(p, 2);
      p += __shfl_xor(p, 4); p += __shfl_xor(p, 8);
      if (c == 0) red[mloc][wc] = p;
    }
  }
  __syncthreads();
  if (tid < 128)
    scorepart[(size_t)nt * M_ + m0 + tid] = red[tid][0] + red[tid][1];
}

// ---------------- K2 fallback (f32 vector) ----------------
__global__ __launch_bounds__(256) void k2_gemm_score(
    const float* __restrict__ enc, const float* __restrict__ aW1,
    const float* __restrict__ hpart, const float* __restrict__ aW2,
    float* __restrict__ scorepart) {
  __shared__ float As[32][68];
  __shared__ float Bs[32][68];
  __shared__ float red[64][17];
  int m0 = blockIdx.x * 64;
  int n0 = blockIdx.y * 64;
  int tid = threadIdx.x;
  int ty = tid >> 4, tx = tid & 15;
  float acc[4][4] = {};
  for (int k0 = 0; k0 < H2; k0 += 32) {
    #pragma unroll
    for (int l = 0; l < 2; ++l) {
      int fi = tid + l * 256;
      int m = fi >> 3;
      int kq = (fi & 7) * 4;
      const float4 v = *(const float4*)&enc[(size_t)(m0 + m) * H2 + k0 + kq];
      As[kq + 0][m] = v.x; As[kq + 1][m] = v.y; As[kq + 2][m] = v.z; As[kq + 3][m] = v.w;
      const float4 u = *(const float4*)&aW1[(size_t)(n0 + m) * H3 + H_ + k0 + kq];
      Bs[kq + 0][m] = u.x; Bs[kq + 1][m] = u.y; Bs[kq + 2][m] = u.z; Bs[kq + 3][m] = u.w;
    }
    __syncthreads();
    #pragma unroll
    for (int kk = 0; kk < 32; ++kk) {
      float4 av = *(const float4*)&As[kk][ty * 4];
      float4 bv = *(const float4*)&Bs[kk][tx * 4];
      float a[4] = {av.x, av.y, av.z, av.w};
      float b[4] = {bv.x, bv.y, bv.z, bv.w};
      #pragma unroll
      for (int i = 0; i < 4; ++i)
        #pragma unroll
        for (int j = 0; j < 4; ++j)
          acc[i][j] += a[i] * b[j];
    }
    __syncthreads();
  }
  #pragma unroll
  for (int i = 0; i < 4; ++i) {
    int m = m0 + ty * 4 + i;
    int bb = m & 63;
    float p = 0.f;
    #pragma unroll
    for (int j = 0; j < 4; ++j) {
      int n = n0 + tx * 4 + j;
      p += aW2[n] * tanhf(hpart[bb * H_ + n] + acc[i][j]);
    }
    red[ty * 4 + i][tx] = p;
  }
  __syncthreads();
  if (tid < 64) {
    float s = 0.f;
    #pragma unroll
    for (int j = 0; j < 16; ++j) s += red[tid][j];
    scorepart[(size_t)blockIdx.y * M_ + m0 + tid] = s;
  }
}

// ---------------- K3 (slow path only) ----------------
__global__ void k3_softmax(const float* __restrict__ scorepart, const float* __restrict__ ab2,
                           float* __restrict__ w, int nb) {
  int b = blockIdx.x;
  int t = threadIdx.x;
  float s = ab2[0];
  for (int k = 0; k < nb; ++k) s += scorepart[k * M_ + t * B_ + b];
  __shared__ float sm[128];
  sm[t] = s; __syncthreads();
  for (int off = 64; off; off >>= 1) {
    if (t < off) sm[t] = fmaxf(sm[t], sm[t + off]);
    __syncthreads();
  }
  float mx = sm[0]; __syncthreads();
  float e = expf(s - mx);
  sm[t] = e; __syncthreads();
  for (int off = 64; off; off >>= 1) {
    if (t < off) sm[t] += sm[t + off];
    __syncthreads();
  }
  w[t * B_ + b] = e / sm[0];
}

// ---------------- K4c (+REP probe) ----------------
__global__ __launch_bounds__(256) void k4c_ctx(
    const unsigned short* __restrict__ encb, const float* __restrict__ scorepart,
    const float* __restrict__ ab2, const int* __restrict__ input,
    const float* __restrict__ emb_W, float* __restrict__ rnn_in,
    unsigned short* __restrict__ xb) {
  int b = blockIdx.y;
  for (int rep = 0; rep < REP_K4; ++rep) {
    __syncthreads();
    if (blockIdx.x == 4) {
      int tok = input[b];
      for (int c = threadIdx.x; c < E_; c += 256)
        rnn_in[b * EC + c] = emb_W[(size_t)tok * E_ + c];
      continue;
    }
    int t = threadIdx.x;
    __shared__ float wl[TX];
    __shared__ float sm[TX];
    float s = 0.f;
    if (t < TX) {
      s = ab2[0];
      #pragma unroll
      for (int k = 0; k < 8; ++k) s += scorepart[k * M_ + t * B_ + b];
      sm[t] = s;
    }
    __syncthreads();
    for (int off = 64; off; off >>= 1) {
      if (t < off) sm[t] = fmaxf(sm[t], sm[t + off]);
      __syncthreads();
    }
    float mx = sm[0]; __syncthreads();
    float e = 0.f;
    if (t < TX) { e = expf(s - mx); sm[t] = e; }
    __syncthreads();
    for (int off = 64; off; off >>= 1) {
      if (t < off) sm[t] += sm[t + off];
      __syncthreads();
    }
    if (t < TX) wl[t] = e / sm[0];
    __syncthreads();

    int kp = blockIdx.x * 256 + threadIdx.x;
    float a0 = 0.f, a1 = 0.f;
    for (int tt = 0; tt < TX; ++tt) {
      unsigned int u = *(const unsigned int*)&encb[((size_t)tt * B_ + b) * H2 + kp * 2];
      float e0 = __builtin_bit_cast(float, u << 16);
      float e1 = __builtin_bit_cast(float, u & 0xffff0000u);
      float wt = wl[tt];
      a0 += wt * e0; a1 += wt * e1;
    }
    float2 o; o.x = a0; o.y = a1;
    *(float2*)&rnn_in[b * EC + E_ + kp * 2] = o;
    unsigned int ob = (unsigned int)f2bf(a0) | ((unsigned int)f2bf(a1) << 16);
    *(unsigned int*)&xb[b * H3 + H_ + kp * 2] = ob;
  }
}

// ---------------- slow-path K4/K5a ----------------
__global__ void k4_context(const float* __restrict__ enc, const float* __restrict__ w,
                           float* __restrict__ context) {
  int b = blockIdx.y;
  int k = blockIdx.x * 256 + threadIdx.x;
  __shared__ float wl[TX];
  if (threadIdx.x < TX) wl[threadIdx.x] = w[threadIdx.x * B_ + b];
  __syncthreads();
  float acc = 0.f;
  for (int t = 0; t < TX; ++t)
    acc += wl[t] * enc[((size_t)t * B_ + b) * H2 + k];
  context[b * H2 + k] = acc;
}
__global__ void k5a_rnnin(const int* __restrict__ input, const float* __restrict__ emb_W,
                          const float* __restrict__ context, float* __restrict__ rnn_in) {
  int b = blockIdx.x;
  int tok = input[b];
  for (int c = threadIdx.x; c < EC; c += blockDim.x)
    rnn_in[b * EC + c] = (c < E_) ? emb_W[(size_t)tok * E_ + c] : context[b * H2 + (c - E_)];
}

// ---------------- shared gemmT body ----------------
__device__ __forceinline__ void gemmT_body(const float* __restrict__ x,
    const float* __restrict__ W, int lda, const float* __restrict__ bias,
    float* __restrict__ po, int N, int K, int kbeg, int kend, bool addb,
    float* __restrict__ Ws) {
  int tid = threadIdx.x;
  int b = tid & 63, g = tid >> 6;
  int n0 = blockIdx.x * 64;
  float acc[16] = {};
  const float4* xv = (const float4*)(x + (size_t)b * K);
  for (int k0 = kbeg; k0 < kend; k0 += 128) {
    __syncthreads();
    #pragma unroll
    for (int l = 0; l < 8; ++l) {
      int f = l * 256 + tid;
      int row = f >> 5, c4 = f & 31;
      float4 v = *(const float4*)&W[(size_t)(n0 + row) * lda + k0 + c4 * 4];
      *(float4*)&Ws[row * WST + c4 * 4] = v;
    }
    __syncthreads();
    #pragma unroll
    for (int kb = 0; kb < 128; kb += 16) {
      float4 x0 = xv[(k0 + kb) / 4 + 0];
      float4 x1 = xv[(k0 + kb) / 4 + 1];
      float4 x2 = xv[(k0 + kb) / 4 + 2];
      float4 x3 = xv[(k0 + kb) / 4 + 3];
      #pragma unroll
      for (int i = 0; i < 16; ++i) {
        const float* wr = &Ws[(g * 16 + i) * WST + kb];
        float4 w0 = *(const float4*)(wr + 0);
        float4 w1 = *(const float4*)(wr + 4);
        float4 w2 = *(const float4*)(wr + 8);
        float4 w3 = *(const float4*)(wr + 12);
        acc[i] += x0.x*w0.x + x0.y*w0.y + x0.z*w0.z + x0.w*w0.w
                + x1.x*w1.x + x1.y*w1.y + x1.z*w1.z + x1.w*w1.w
                + x2.x*w2.x + x2.y*w2.y + x2.z*w2.z + x2.w*w2.w
                + x3.x*w3.x + x3.y*w3.y + x3.z*w3.z + x3.w*w3.w;
      }
    }
  }
  #pragma unroll
  for (int i = 0; i < 16; ++i) {
    int n = n0 + g * 16 + i;
    float v = acc[i];
    if (addb) v += bias[n];
    po[(size_t)b * N + n] = v;
  }
}

// merged gi+gh (+REP probe)
__global__ __launch_bounds__(256) void k_gates_gemm(
    const float* __restrict__ rnn_in, const float* __restrict__ Wih, const float* __restrict__ bih,
    const float* __restrict__ hidden, const float* __restrict__ Whh, const float* __restrict__ bhh,
    float* __restrict__ gi, float* __restrict__ gh) {
  __shared__ float Ws[64 * WST];
  int s = blockIdx.y;
  for (int rep = 0; rep < REP_KG; ++rep) {
    __syncthreads();
    if (s < 5)
      gemmT_body(rnn_in, Wih, EC, bih, gi + (size_t)s * B_ * H3, H3, EC, s * 512, s * 512 + 512, s == 0, Ws);
    else {
      int t = s - 5;
      gemmT_body(hidden, Whh, H_, bhh, gh + (size_t)t * B_ * H3, H3, H_, t * 512, t * 512 + 512, t == 0, Ws);
    }
  }
}

// legacy standalone (slow path)
__global__ __launch_bounds__(256) void k_gemm_T(
    const float* __restrict__ x, const float* __restrict__ W,
    const float* __restrict__ bias, float* __restrict__ out, int N, int K) {
  __shared__ float Ws[64 * WST];
  int ks = blockIdx.y;
  int kchunk = K / gridDim.y;
  gemmT_body(x, W, K, bias, out + (size_t)ks * 64 * N, N, K, ks * kchunk, ks * kchunk + kchunk, ks == 0, Ws);
}

// ---------------- K5c ----------------
__global__ void k5c_gates(const float* __restrict__ gip, const float* __restrict__ ghp,
                          int gis, int ghs, int do_ctx,
                          const float* __restrict__ hidden, const float* __restrict__ context,
                          float* __restrict__ hnew_out, unsigned short* __restrict__ xb) {
  int b = blockIdx.x;
  for (int h = threadIdx.x; h < H_; h += blockDim.x) {
    float ir = 0.f, iz = 0.f, inn = 0.f;
    for (int s = 0; s < gis; ++s) {
      const float* gb = gip + (size_t)s * B_ * H3 + (size_t)b * H3;
      ir += gb[h]; iz += gb[H_ + h]; inn += gb[H2 + h];
    }
    float hr = 0.f, hz = 0.f, hn = 0.f;
    for (int s = 0; s < ghs; ++s) {
      const float* gb = ghp + (size_t)s * B_ * H3 + (size_t)b * H3;
      hr += gb[h]; hz += gb[H_ + h]; hn += gb[H2 + h];
    }
    float r = 1.f / (1.f + expf(-(ir + hr)));
    float z = 1.f / (1.f + expf(-(iz + hz)));
    float n = tanhf(inn + r * hn);
    float hv = hidden[b * H_ + h];
    float hnew = (1.f - z) * n + z * hv;
    hnew_out[b * H_ + h] = hnew;
    xb[b * H3 + h] = f2bf(hnew);
  }
  if (do_ctx)
    for (int c = threadIdx.x; c < H2; c += blockDim.x)
      xb[b * H3 + H_ + c] = f2bf(context[b * H2 + c]);
}

// ---------------- k6 helper ----------------
__device__ __forceinline__ void k6_stage(float4 wa, float4 wb,
    const unsigned short* __restrict__ xp, int off,
    f32x4& a0, f32x4& a1, f32x4& a2, f32x4& a3) {
  u16x8 bu;
  bu[0] = f2bf(wa.x); bu[1] = f2bf(wa.y); bu[2] = f2bf(wa.z); bu[3] = f2bf(wa.w);
  bu[4] = f2bf(wb.x); bu[5] = f2bf(wb.y); bu[6] = f2bf(wb.z); bu[7] = f2bf(wb.w);
  bf16x8 bf = __builtin_bit_cast(bf16x8, bu);
  u16x8 x0 = *(const u16x8*)(xp + off);
  u16x8 x1 = *(const u16x8*)(xp + 16 * H3 + off);
  u16x8 x2 = *(const u16x8*)(xp + 32 * H3 + off);
  u16x8 x3 = *(const u16x8*)(xp + 48 * H3 + off);
  a0 = __builtin_amdgcn_mfma_f32_16x16x32_bf16(__builtin_bit_cast(bf16x8, x0), bf, a0, 0, 0, 0);
  a1 = __builtin_amdgcn_mfma_f32_16x16x32_bf16(__builtin_bit_cast(bf16x8, x1), bf, a1, 0, 0, 0);
  a2 = __builtin_amdgcn_mfma_f32_16x16x32_bf16(__builtin_bit_cast(bf16x8, x2), bf, a2, 0, 0, 0);
  a3 = __builtin_amdgcn_mfma_f32_16x16x32_bf16(__builtin_bit_cast(bf16x8, x3), bf, a3, 0, 0, 0);
}

// ---------------- K6 v5 (unchanged) ----------------
__global__ __launch_bounds__(256) void k6_split(
    const unsigned short* __restrict__ xb, const float* __restrict__ W,
    float* __restrict__ part) {
  __shared__ __align__(16) float Ws[64 * 128];
  __shared__ __align__(16) unsigned short Xs[64 * 128];
  int tid = threadIdx.x;
  int wv = tid >> 6, lane = tid & 63;
  int r = lane & 15, kg = lane >> 4;
  int n = blockIdx.x * 64 + wv * 16 + r;
  int ks = blockIdx.y;
  const int KC = H3 / NS;                   // 768
  int kbase = ks * KC;
  f32x4 a0 = {0.f, 0.f, 0.f, 0.f}, a1 = a0, a2 = a0, a3 = a0;

  for (int ch = 0; ch < KC; ch += 128) {
    __syncthreads();
    #pragma unroll
    for (int i = 0; i < 8; ++i) {
      int rowW = (wv * 8 + i) * 2 + (lane >> 5);
      int sc = (lane & 31) ^ (rowW & 15);
      gload16(&W[(size_t)(blockIdx.x * 64 + rowW) * H3 + kbase + ch + sc * 4],
              &Ws[(wv * 8 + i) * 256]);
    }
    #pragma unroll
    for (int i = 0; i < 4; ++i) {
      int rowX = (wv * 4 + i) * 4 + (lane >> 4);
      int sc = (lane & 15) ^ (rowX & 15);
      gload16(&xb[(size_t)rowX * H3 + kbase + ch + sc * 8],
              &Xs[(wv * 4 + i) * 512]);
    }
    __syncthreads();
    #pragma unroll
    for (int s = 0; s < 4; ++s) {
      int uw0 = (s * 8 + kg * 2) ^ r;
      int uw1 = (s * 8 + kg * 2 + 1) ^ r;
      int rw = wv * 16 + r;
      float4 wa = *(const float4*)&Ws[rw * 128 + uw0 * 4];
      float4 wb = *(const float4*)&Ws[rw * 128 + uw1 * 4];
      u16x8 bu;
      bu[0] = f2bf(wa.x); bu[1] = f2bf(wa.y); bu[2] = f2bf(wa.z); bu[3] = f2bf(wa.w);
      bu[4] = f2bf(wb.x); bu[5] = f2bf(wb.y); bu[6] = f2bf(wb.z); bu[7] = f2bf(wb.w);
      bf16x8 bf = __builtin_bit_cast(bf16x8, bu);
      int ux = (s * 4 + kg) ^ r;
      u16x8 x0 = *(const u16x8*)&Xs[(r)      * 128 + ux * 8];
      u16x8 x1 = *(const u16x8*)&Xs[(16 + r) * 128 + ux * 8];
      u16x8 x2 = *(const u16x8*)&Xs[(32 + r) * 128 + ux * 8];
      u16x8 x3 = *(const u16x8*)&Xs[(48 + r) * 128 + ux * 8];
      a0 = __builtin_amdgcn_mfma_f32_16x16x32_bf16(__builtin_bit_cast(bf16x8, x0), bf, a0, 0, 0, 0);
      a1 = __builtin_amdgcn_mfma_f32_16x16x32_bf16(__builtin_bit_cast(bf16x8, x1), bf, a1, 0, 0, 0);
      a2 = __builtin_amdgcn_mfma_f32_16x16x32_bf16(__builtin_bit_cast(bf16x8, x2), bf, a2, 0, 0, 0);
      a3 = __builtin_amdgcn_mfma_f32_16x16x32_bf16(__builtin_bit_cast(bf16x8, x3), bf, a3, 0, 0, 0);
    }
  }
  float* po = part + (size_t)ks * B_ * KY;
  int r0 = kg * 4;
  #pragma unroll
  for (int rr = 0; rr < 4; ++rr) {
    po[(size_t)(r0 + rr) * KY + n]      = a0[rr];
    po[(size_t)(16 + r0 + rr) * KY + n] = a1[rr];
    po[(size_t)(32 + r0 + rr) * KY + n] = a2[rr];
    po[(size_t)(48 + r0 + rr) * KY + n] = a3[rr];
  }
}

// ---------------- K6 legacy (slow path) ----------------
__global__ __launch_bounds__(256) void k6_lsm_mfma(
    const unsigned short* __restrict__ xb, const float* __restrict__ W,
    const float* __restrict__ bias, float* __restrict__ out) {
  int tid = threadIdx.x;
  int wv = tid >> 6, lane = tid & 63;
  int n = blockIdx.x * 64 + wv * 16 + (lane & 15);
  int kg = lane >> 4;
  const float* wp = W + (size_t)n * H3 + kg * 8;
  const unsigned short* xp = xb + (size_t)(lane & 15) * H3 + kg * 8;
  f32x4 a0 = {0.f, 0.f, 0.f, 0.f}, a1 = a0, a2 = a0, a3 = a0;
  for (int k0 = 0; k0 < H3; k0 += 128) {
    float4 wA0 = *(const float4*)(wp + k0 +   0);
    float4 wB0 = *(const float4*)(wp + k0 +   4);
    float4 wA1 = *(const float4*)(wp + k0 +  32);
    float4 wB1 = *(const float4*)(wp + k0 +  36);
    float4 wA2 = *(const float4*)(wp + k0 +  64);
    float4 wB2 = *(const float4*)(wp + k0 +  68);
    float4 wA3 = *(const float4*)(wp + k0 +  96);
    float4 wB3 = *(const float4*)(wp + k0 + 100);
    k6_stage(wA0, wB0, xp, k0 +  0, a0, a1, a2, a3);
    k6_stage(wA1, wB1, xp, k0 + 32, a0, a1, a2, a3);
    k6_stage(wA2, wB2, xp, k0 + 64, a0, a1, a2, a3);
    k6_stage(wA3, wB3, xp, k0 + 96, a0, a1, a2, a3);
  }
  float bv = bias[n];
  int r0 = kg * 4;
  #pragma unroll
  for (int r = 0; r < 4; ++r) {
    out[(size_t)(r0 + r) * KY + n]      = a0[r] + bv;
    out[(size_t)(16 + r0 + r) * KY + n] = a1[r] + bv;
    out[(size_t)(32 + r0 + r) * KY + n] = a2[r] + bv;
    out[(size_t)(48 + r0 + r) * KY + n] = a3[r] + bv;
  }
}

// ---------------- K7a (+REP probe) ----------------
__global__ __launch_bounds__(256) void k7a(const float* __restrict__ part,
                                           const float* __restrict__ bias,
                                           float* __restrict__ out,
                                           float* __restrict__ pm, float* __restrict__ ps) {
  int b = blockIdx.y, q = blockIdx.x;
  float* orow = out + (size_t)b * KY;
  int base = q * (KY / 4);
  int end  = base + (KY / 4);
  __shared__ float sm[256];
  for (int rep = 0; rep < REP_K7; ++rep) {
    __syncthreads();
    float mx = -1e30f;
    for (int k = base + threadIdx.x; k < end; k += 256) {
      float v = bias[k];
      #pragma unroll
      for (int s = 0; s < NS; ++s)
        v += part[(size_t)s * B_ * KY + (size_t)b * KY + k];
      orow[k] = v;
      mx = fmaxf(mx, v);
    }
    sm[threadIdx.x] = mx; __syncthreads();
    for (int off = 128; off; off >>= 1) {
      if (threadIdx.x < off) sm[threadIdx.x] = fmaxf(sm[threadIdx.x], sm[threadIdx.x + off]);
      __syncthreads();
    }
    float M = sm[0]; __syncthreads();
    float s = 0.f;
    for (int k = base + threadIdx.x; k < end; k += 256)
      s += expf(orow[k] - M);
    sm[threadIdx.x] = s; __syncthreads();
    for (int off = 128; off; off >>= 1) {
      if (threadIdx.x < off) sm[threadIdx.x] += sm[threadIdx.x + off];
      __syncthreads();
    }
    if (threadIdx.x == 0) { pm[b * 4 + q] = M; ps[b * 4 + q] = sm[0]; }
  }
}

// ---------------- K8f ----------------
__global__ void k8f_out(float* __restrict__ outp, const float* __restrict__ pm,
                        const float* __restrict__ ps) {
  int b = blockIdx.y;
  float m0 = pm[b*4], m1 = pm[b*4+1], m2 = pm[b*4+2], m3 = pm[b*4+3];
  float M = fmaxf(fmaxf(m0, m1), fmaxf(m2, m3));
  float s = ps[b*4]   * expf(m0 - M) + ps[b*4+1] * expf(m1 - M)
          + ps[b*4+2] * expf(m2 - M) + ps[b*4+3] * expf(m3 - M);
  float lse = M + logf(s);
  int k = blockIdx.x * 256 + threadIdx.x;
  size_t idx = (size_t)b * KY + k;
  outp[idx] = outp[idx] - lse;
}

// ---------------- slow-path K7/K8 ----------------
__global__ void k7_lse(const float* __restrict__ logits, float* __restrict__ lse) {
  int b = blockIdx.x;
  const float* row = logits + (size_t)b * KY;
  __shared__ float sm[256];
  float mx = -1e30f;
  for (int k = threadIdx.x; k < KY; k += 256) mx = fmaxf(mx, row[k]);
  sm[threadIdx.x] = mx; __syncthreads();
  for (int off = 128; off; off >>= 1) {
    if (threadIdx.x < off) sm[threadIdx.x] = fmaxf(sm[threadIdx.x], sm[threadIdx.x + off]);
    __syncthreads();
  }
  mx = sm[0]; __syncthreads();
  float s = 0.f;
  for (int k = threadIdx.x; k < KY; k += 256) s += expf(row[k] - mx);
  sm[threadIdx.x] = s; __syncthreads();
  for (int off = 128; off; off >>= 1) {
    if (threadIdx.x < off) sm[threadIdx.x] += sm[threadIdx.x + off];
    __syncthreads();
  }
  if (threadIdx.x == 0) lse[b] = mx + logf(sm[0]);
}
__global__ void k8_out(float* __restrict__ outp, const float* __restrict__ lse) {
  int b = blockIdx.y;
  int k = blockIdx.x * 256 + threadIdx.x;
  size_t idx = (size_t)b * KY + k;
  outp[idx] = outp[idx] - lse[b];
}

extern "C" void kernel_launch(void* const* d_in, const int* in_sizes, int n_in,
                              void* d_out, int out_size, void* d_ws, size_t ws_size,
                              hipStream_t stream) {
  const int*   input  = (const int*)  d_in[0];
  const float* hidden = (const float*)d_in[1];
  const float* enc    = (const float*)d_in[2];
  const float* emb_W  = (const float*)d_in[3];
  const float* Wih    = (const float*)d_in[4];
  const float* Whh    = (const float*)d_in[5];
  const float* bih    = (const float*)d_in[6];
  const float* bhh    = (const float*)d_in[7];
  const float* lsm_W  = (const float*)d_in[8];
  const float* lsm_b  = (const float*)d_in[9];
  const float* aW1    = (const float*)d_in[10];
  const float* ab1    = (const float*)d_in[11];
  const float* aW2    = (const float*)d_in[12];
  const float* ab2    = (const float*)d_in[13];

  float* out   = (float*)d_out;
  float* hnew  = out + (size_t)B_ * KY;

  int gis = 5, ghs = 2;
  size_t base_fast = 65536 + 131072 + 8192 + 131072 + 163840
                   + (size_t)gis * 196608 + (size_t)ghs * 196608
                   + 98304 + 64 + 256 + 256 + (size_t)NS * B_ * KY;
  size_t need_fast = (base_fast + 8388608 + 1048576) * 4;
  int fast = (ws_size >= need_fast);
  if (!fast) {
    size_t base_slow = 65536 + 131072 + 8192 + 131072 + 163840
                     + (size_t)gis * 196608 + (size_t)ghs * 196608 + 98304 + 64;
    if (ws_size < base_slow * 4) { gis = 1; ghs = 1; }
  }

  float* ws = (float*)d_ws;
  unsigned short* encb = (unsigned short*)ws;
  unsigned short* w1b  = encb + (fast ? 16777216 : 0);
  float* fbase = fast ? (float*)(w1b + 2097152) : ws;
  float* hpart     = fbase;
  float* scorepart = hpart + 65536;
  float* w         = scorepart + 131072;
  float* context   = w + 8192;
  float* rnn_in    = context + 131072;
  float* gi        = rnn_in + 163840;
  float* gh        = gi + (size_t)gis * 196608;
  unsigned short* xb = (unsigned short*)(gh + (size_t)ghs * 196608);
  float* lse       = (float*)(xb + 196608);
  float* pm        = lse + 64;
  float* ps        = pm + 256;
  float* part      = ps + 256;            // NS*64*32000 f32 (fast only)

  k1_hpart<<<dim3(256, 64), 256, 0, stream>>>(hidden, aW1, ab1, hpart);
  if (fast) {
    kc_all<<<9216, 256, 0, stream>>>(enc, aW1, encb, w1b);
    k2_mfma<<<512, 256, 0, stream>>>(encb, w1b, hpart, aW2, scorepart);
    k4c_ctx<<<dim3(5, B_), 256, 0, stream>>>(encb, scorepart, ab2, input, emb_W, rnn_in, xb);
    k_gates_gemm<<<dim3(H3 / 64, 7), 256, 0, stream>>>(rnn_in, Wih, bih, hidden, Whh, bhh, gi, gh);
    k5c_gates<<<B_, 256, 0, stream>>>(gi, gh, gis, ghs, 0, hidden, context, hnew, xb);
    k6_split<<<dim3(KY / 64, NS), 256, 0, stream>>>(xb, lsm_W, part);
    k7a<<<dim3(4, B_), 256, 0, stream>>>(part, lsm_b, out, pm, ps);
    k8f_out<<<dim3(KY / 256, B_), 256, 0, stream>>>(out, pm, ps);
  } else {
    k2_gemm_score<<<dim3(M_ / 64, 16), 256, 0, stream>>>(enc, aW1, hpart, aW2, scorepart);
    k3_softmax<<<B_, TX, 0, stream>>>(scorepart, ab2, w, 16);
    k4_context<<<dim3(H2 / 256, B_), 256, 0, stream>>>(enc, w, context);
    k5a_rnnin<<<B_, 256, 0, stream>>>(input, emb_W, context, rnn_in);
    k_gemm_T<<<dim3(H3 / 64, gis), 256, 0, stream>>>(rnn_in, Wih, bih, gi, H3, EC);
    k_gemm_T<<<dim3(H3 / 64, ghs), 256, 0, stream>>>(hidden, Whh, bhh, gh, H3, H_);
    k5c_gates<<<B_, 256, 0, stream>>>(gi, gh, gis, ghs, 1, hidden, context, hnew, xb);
    k6_lsm_mfma<<<KY / 64, 256, 0, stream>>>(xb, lsm_W, lsm_b, out);
    k7_lse<<<B_, 256, 0, stream>>>(out, lse);
    k8_out<<<dim3(KY / 256, B_), 256, 0, stream>>>(out, lse);
  }
}

// Round 14
// 267.283 us; speedup vs baseline: 16.8311x; 16.8311x over previous
//
#include <hip/hip_runtime.h>
#include <hip/hip_bf16.h>

#define B_  64
#define TX  128
#define H_  1024
#define E_  512
#define KY  32000
#define H2  2048   // 2H
#define H3  3072   // 3H
#define EC  2560   // E+2H
#define M_  (TX*B_) // 8192
#define WST 132    // LDS row stride for f32 W tile (gemmT, slow path)
#define NS  4      // K-splits for lsm GEMM (KC=768)

typedef __bf16 bf16x8 __attribute__((ext_vector_type(8)));
typedef unsigned short u16x8 __attribute__((ext_vector_type(8)));
typedef float f32x4 __attribute__((ext_vector_type(4)));

// f32 -> bf16 round-to-nearest-even
__device__ __forceinline__ unsigned short f2bf(float f) {
  unsigned int u = __builtin_bit_cast(unsigned int, f);
  u += 0x7fff + ((u >> 16) & 1);
  return (unsigned short)(u >> 16);
}

// async global->LDS, 16B per lane
__device__ __forceinline__ void gload16(const void* g, void* l) {
  __builtin_amdgcn_global_load_lds(
      (const __attribute__((address_space(1))) unsigned int*)g,
      (__attribute__((address_space(3))) unsigned int*)l, 16, 0, 0);
}

// ---------------- merged convert: enc->encb, aW1[:,H:]->w1b, hidden->hb ----------------
__global__ void kc_all(const float* __restrict__ enc, const float* __restrict__ aW1,
                       const float* __restrict__ hidden,
                       unsigned short* __restrict__ encb, unsigned short* __restrict__ w1b,
                       unsigned short* __restrict__ hb) {
  size_t gid = (size_t)blockIdx.x * 256 + threadIdx.x;
  if (gid < 2097152) {
    size_t i = gid * 8;
    float4 v0 = *(const float4*)(enc + i);
    float4 v1 = *(const float4*)(enc + i + 4);
    u16x8 o;
    o[0]=f2bf(v0.x); o[1]=f2bf(v0.y); o[2]=f2bf(v0.z); o[3]=f2bf(v0.w);
    o[4]=f2bf(v1.x); o[5]=f2bf(v1.y); o[6]=f2bf(v1.z); o[7]=f2bf(v1.w);
    *(u16x8*)(encb + i) = o;
  } else if (gid < 2359296) {
    size_t idx = (gid - 2097152) * 8;
    int row = (int)(idx >> 11);
    int col = (int)(idx & 2047);
    const float* s = aW1 + (size_t)row * H3 + H_ + col;
    float4 v0 = *(const float4*)(s);
    float4 v1 = *(const float4*)(s + 4);
    u16x8 o;
    o[0]=f2bf(v0.x); o[1]=f2bf(v0.y); o[2]=f2bf(v0.z); o[3]=f2bf(v0.w);
    o[4]=f2bf(v1.x); o[5]=f2bf(v1.y); o[6]=f2bf(v1.z); o[7]=f2bf(v1.w);
    *(u16x8*)(w1b + idx) = o;
  } else {
    size_t idx = (gid - 2359296) * 8;   // hidden: 65536 elems = 8192 threads
    if (idx < 65536) {
      float4 v0 = *(const float4*)(hidden + idx);
      float4 v1 = *(const float4*)(hidden + idx + 4);
      u16x8 o;
      o[0]=f2bf(v0.x); o[1]=f2bf(v0.y); o[2]=f2bf(v0.z); o[3]=f2bf(v0.w);
      o[4]=f2bf(v1.x); o[5]=f2bf(v1.y); o[6]=f2bf(v1.z); o[7]=f2bf(v1.w);
      *(u16x8*)(hb + idx) = o;
    }
  }
}

// ---------------- K1: hpart[b][h] = ab1[h] + hidden[b,:] . aW1[h, :H] ----------------
__global__ void k1_hpart(const float* __restrict__ hidden, const float* __restrict__ aW1,
                         const float* __restrict__ ab1, float* __restrict__ hpart) {
  int b = blockIdx.y;
  int wave = threadIdx.x >> 6;
  int lane = threadIdx.x & 63;
  int h = blockIdx.x * 4 + wave;
  const float* wrow = aW1 + (size_t)h * H3;
  const float* hrow = hidden + b * H_;
  float acc = 0.f;
  for (int j = 0; j < H_ / 64; ++j) {
    int i = j * 64 + lane;
    acc += hrow[i] * wrow[i];
  }
  for (int off = 32; off; off >>= 1) acc += __shfl_down(acc, off);
  if (lane == 0) hpart[b * H_ + h] = acc + ab1[h];
}

// ---------------- K2 v3: 128x128 tile, BK=64, gload_lds + both-sides XOR swizzle ----------------
__global__ __launch_bounds__(256) void k2_mfma(
    const unsigned short* __restrict__ encb, const unsigned short* __restrict__ w1b,
    const float* __restrict__ hpart, const float* __restrict__ aW2,
    float* __restrict__ scorepart) {
  __shared__ __align__(16) unsigned short As[128 * 64];
  __shared__ __align__(16) unsigned short Bs[128 * 64];
  __shared__ float red[128][2];
  int wg = blockIdx.x;
  int swz = (wg & 7) * 64 + (wg >> 3);
  int mt = swz >> 3, nt = swz & 7;
  int m0 = mt * 128, n0 = nt * 128;
  int tid = threadIdx.x;
  int lane = tid & 63, wid = tid >> 6;
  int wr = wid >> 1, wc = wid & 1;
  f32x4 z = {0.f, 0.f, 0.f, 0.f};
  f32x4 acc[4][4];
  #pragma unroll
  for (int i = 0; i < 4; ++i)
    #pragma unroll
    for (int j = 0; j < 4; ++j) acc[i][j] = z;

  int srow = lane >> 3;
  int scol = ((lane & 7) ^ srow) * 8;
  for (int k0 = 0; k0 < H2; k0 += 64) {
    __syncthreads();
    #pragma unroll
    for (int i = 0; i < 4; ++i) {
      int ci = wid * 4 + i;
      int row = ci * 8 + srow;
      gload16(&encb[(size_t)(m0 + row) * H2 + k0 + scol], &As[ci * 512]);
      gload16(&w1b [(size_t)(n0 + row) * H2 + k0 + scol], &Bs[ci * 512]);
    }
    __syncthreads();
    #pragma unroll
    for (int ks = 0; ks < 2; ++ks) {
      bf16x8 af[4], bfr[4];
      #pragma unroll
      for (int i = 0; i < 4; ++i) {
        int ra = wr * 64 + i * 16 + (lane & 15);
        int rb = wc * 64 + i * 16 + (lane & 15);
        int og = (ks * 4 + (lane >> 4));
        af[i]  = *(const bf16x8*)&As[ra * 64 + ((og ^ (ra & 7)) * 8)];
        bfr[i] = *(const bf16x8*)&Bs[rb * 64 + ((og ^ (rb & 7)) * 8)];
      }
      #pragma unroll
      for (int mi = 0; mi < 4; ++mi)
        #pragma unroll
        for (int ni = 0; ni < 4; ++ni)
          acc[mi][ni] = __builtin_amdgcn_mfma_f32_16x16x32_bf16(af[mi], bfr[ni], acc[mi][ni], 0, 0, 0);
    }
  }
  int q = lane >> 4, c = lane & 15;
  #pragma unroll
  for (int mi = 0; mi < 4; ++mi) {
    #pragma unroll
    for (int r = 0; r < 4; ++r) {
      int mloc = wr * 64 + mi * 16 + q * 4 + r;
      int b = (mi * 16 + q * 4 + r) & 63;
      float p = 0.f;
      #pragma unroll
      for (int ni = 0; ni < 4; ++ni) {
        int n = n0 + wc * 64 + ni * 16 + c;
        p += aW2[n] * tanhf(hpart[b * H_ + n] + acc[mi][ni][r]);
      }
      p += __shfl_xor(p, 1); p += __shfl_xor(p, 2);
      p += __shfl_xor(p, 4); p += __shfl_xor(p, 8);
      if (c == 0) red[mloc][wc] = p;
    }
  }
  __syncthreads();
  if (tid < 128)
    scorepart[(size_t)nt * M_ + m0 + tid] = red[tid][0] + red[tid][1];
}

// ---------------- K2 fallback (f32 vector) ----------------
__global__ __launch_bounds__(256) void k2_gemm_score(
    const float* __restrict__ enc, const float* __restrict__ aW1,
    const float* __restrict__ hpart, const float* __restrict__ aW2,
    float* __restrict__ scorepart) {
  __shared__ float As[32][68];
  __shared__ float Bs[32][68];
  __shared__ float red[64][17];
  int m0 = blockIdx.x * 64;
  int n0 = blockIdx.y * 64;
  int tid = threadIdx.x;
  int ty = tid >> 4, tx = tid & 15;
  float acc[4][4] = {};
  for (int k0 = 0; k0 < H2; k0 += 32) {
    #pragma unroll
    for (int l = 0; l < 2; ++l) {
      int fi = tid + l * 256;
      int m = fi >> 3;
      int kq = (fi & 7) * 4;
      const float4 v = *(const float4*)&enc[(size_t)(m0 + m) * H2 + k0 + kq];
      As[kq + 0][m] = v.x; As[kq + 1][m] = v.y; As[kq + 2][m] = v.z; As[kq + 3][m] = v.w;
      const float4 u = *(const float4*)&aW1[(size_t)(n0 + m) * H3 + H_ + k0 + kq];
      Bs[kq + 0][m] = u.x; Bs[kq + 1][m] = u.y; Bs[kq + 2][m] = u.z; Bs[kq + 3][m] = u.w;
    }
    __syncthreads();
    #pragma unroll
    for (int kk = 0; kk < 32; ++kk) {
      float4 av = *(const float4*)&As[kk][ty * 4];
      float4 bv = *(const float4*)&Bs[kk][tx * 4];
      float a[4] = {av.x, av.y, av.z, av.w};
      float b[4] = {bv.x, bv.y, bv.z, bv.w};
      #pragma unroll
      for (int i = 0; i < 4; ++i)
        #pragma unroll
        for (int j = 0; j < 4; ++j)
          acc[i][j] += a[i] * b[j];
    }
    __syncthreads();
  }
  #pragma unroll
  for (int i = 0; i < 4; ++i) {
    int m = m0 + ty * 4 + i;
    int bb = m & 63;
    float p = 0.f;
    #pragma unroll
    for (int j = 0; j < 4; ++j) {
      int n = n0 + tx * 4 + j;
      p += aW2[n] * tanhf(hpart[bb * H_ + n] + acc[i][j]);
    }
    red[ty * 4 + i][tx] = p;
  }
  __syncthreads();
  if (tid < 64) {
    float s = 0.f;
    #pragma unroll
    for (int j = 0; j < 16; ++j) s += red[tid][j];
    scorepart[(size_t)blockIdx.y * M_ + m0 + tid] = s;
  }
}

// ---------------- K3 (slow path only) ----------------
__global__ void k3_softmax(const float* __restrict__ scorepart, const float* __restrict__ ab2,
                           float* __restrict__ w, int nb) {
  int b = blockIdx.x;
  int t = threadIdx.x;
  float s = ab2[0];
  for (int k = 0; k < nb; ++k) s += scorepart[k * M_ + t * B_ + b];
  __shared__ float sm[128];
  sm[t] = s; __syncthreads();
  for (int off = 64; off; off >>= 1) {
    if (t < off) sm[t] = fmaxf(sm[t], sm[t + off]);
    __syncthreads();
  }
  float mx = sm[0]; __syncthreads();
  float e = expf(s - mx);
  sm[t] = e; __syncthreads();
  for (int off = 64; off; off >>= 1) {
    if (t < off) sm[t] += sm[t + off];
    __syncthreads();
  }
  w[t * B_ + b] = e / sm[0];
}

// ---------------- K4c (fast): fused softmax+context -> rb[E_:] + xb[H_:]; x=4 embed->rb ----------------
__global__ __launch_bounds__(256) void k4c_ctx(
    const unsigned short* __restrict__ encb, const float* __restrict__ scorepart,
    const float* __restrict__ ab2, const int* __restrict__ input,
    const float* __restrict__ emb_W, unsigned short* __restrict__ rb,
    unsigned short* __restrict__ xb) {
  int b = blockIdx.y;
  if (blockIdx.x == 4) {                     // embed -> rb[b][:E_] (bf16)
    int tok = input[b];
    for (int c = threadIdx.x; c < E_; c += 256)
      rb[b * EC + c] = f2bf(emb_W[(size_t)tok * E_ + c]);
    return;
  }
  int t = threadIdx.x;
  __shared__ float wl[TX];
  __shared__ float sm[TX];
  float s = 0.f;
  if (t < TX) {
    s = ab2[0];
    #pragma unroll
    for (int k = 0; k < 8; ++k) s += scorepart[k * M_ + t * B_ + b];
    sm[t] = s;
  }
  __syncthreads();
  for (int off = 64; off; off >>= 1) {
    if (t < off) sm[t] = fmaxf(sm[t], sm[t + off]);
    __syncthreads();
  }
  float mx = sm[0]; __syncthreads();
  float e = 0.f;
  if (t < TX) { e = expf(s - mx); sm[t] = e; }
  __syncthreads();
  for (int off = 64; off; off >>= 1) {
    if (t < off) sm[t] += sm[t + off];
    __syncthreads();
  }
  if (t < TX) wl[t] = e / sm[0];
  __syncthreads();

  int kp = blockIdx.x * 256 + threadIdx.x;
  float a0 = 0.f, a1 = 0.f;
  for (int tt = 0; tt < TX; ++tt) {
    unsigned int u = *(const unsigned int*)&encb[((size_t)tt * B_ + b) * H2 + kp * 2];
    float e0 = __builtin_bit_cast(float, u << 16);
    float e1 = __builtin_bit_cast(float, u & 0xffff0000u);
    float wt = wl[tt];
    a0 += wt * e0; a1 += wt * e1;
  }
  unsigned int ob = (unsigned int)f2bf(a0) | ((unsigned int)f2bf(a1) << 16);
  *(unsigned int*)&rb[b * EC + E_ + kp * 2] = ob;
  *(unsigned int*)&xb[b * H3 + H_ + kp * 2] = ob;
}

// ---------------- slow-path K4/K5a ----------------
__global__ void k4_context(const float* __restrict__ enc, const float* __restrict__ w,
                           float* __restrict__ context) {
  int b = blockIdx.y;
  int k = blockIdx.x * 256 + threadIdx.x;
  __shared__ float wl[TX];
  if (threadIdx.x < TX) wl[threadIdx.x] = w[threadIdx.x * B_ + b];
  __syncthreads();
  float acc = 0.f;
  for (int t = 0; t < TX; ++t)
    acc += wl[t] * enc[((size_t)t * B_ + b) * H2 + k];
  context[b * H2 + k] = acc;
}
__global__ void k5a_rnnin(const int* __restrict__ input, const float* __restrict__ emb_W,
                          const float* __restrict__ context, float* __restrict__ rnn_in) {
  int b = blockIdx.x;
  int tok = input[b];
  for (int c = threadIdx.x; c < EC; c += blockDim.x)
    rnn_in[b * EC + c] = (c < E_) ? emb_W[(size_t)tok * E_ + c] : context[b * H2 + (c - E_)];
}

// ---------------- shared gemmT body (slow path) ----------------
__device__ __forceinline__ void gemmT_body(const float* __restrict__ x,
    const float* __restrict__ W, int lda, const float* __restrict__ bias,
    float* __restrict__ po, int N, int K, int kbeg, int kend, bool addb,
    float* __restrict__ Ws) {
  int tid = threadIdx.x;
  int b = tid & 63, g = tid >> 6;
  int n0 = blockIdx.x * 64;
  float acc[16] = {};
  const float4* xv = (const float4*)(x + (size_t)b * K);
  for (int k0 = kbeg; k0 < kend; k0 += 128) {
    __syncthreads();
    #pragma unroll
    for (int l = 0; l < 8; ++l) {
      int f = l * 256 + tid;
      int row = f >> 5, c4 = f & 31;
      float4 v = *(const float4*)&W[(size_t)(n0 + row) * lda + k0 + c4 * 4];
      *(float4*)&Ws[row * WST + c4 * 4] = v;
    }
    __syncthreads();
    #pragma unroll
    for (int kb = 0; kb < 128; kb += 16) {
      float4 x0 = xv[(k0 + kb) / 4 + 0];
      float4 x1 = xv[(k0 + kb) / 4 + 1];
      float4 x2 = xv[(k0 + kb) / 4 + 2];
      float4 x3 = xv[(k0 + kb) / 4 + 3];
      #pragma unroll
      for (int i = 0; i < 16; ++i) {
        const float* wr = &Ws[(g * 16 + i) * WST + kb];
        float4 w0 = *(const float4*)(wr + 0);
        float4 w1 = *(const float4*)(wr + 4);
        float4 w2 = *(const float4*)(wr + 8);
        float4 w3 = *(const float4*)(wr + 12);
        acc[i] += x0.x*w0.x + x0.y*w0.y + x0.z*w0.z + x0.w*w0.w
                + x1.x*w1.x + x1.y*w1.y + x1.z*w1.z + x1.w*w1.w
                + x2.x*w2.x + x2.y*w2.y + x2.z*w2.z + x2.w*w2.w
                + x3.x*w3.x + x3.y*w3.y + x3.z*w3.z + x3.w*w3.w;
      }
    }
  }
  #pragma unroll
  for (int i = 0; i < 16; ++i) {
    int n = n0 + g * 16 + i;
    float v = acc[i];
    if (addb) v += bias[n];
    po[(size_t)b * N + n] = v;
  }
}

// legacy standalone (slow path)
__global__ __launch_bounds__(256) void k_gemm_T(
    const float* __restrict__ x, const float* __restrict__ W,
    const float* __restrict__ bias, float* __restrict__ out, int N, int K) {
  __shared__ float Ws[64 * WST];
  int ks = blockIdx.y;
  int kchunk = K / gridDim.y;
  gemmT_body(x, W, K, bias, out + (size_t)ks * 64 * N, N, K, ks * kchunk, ks * kchunk + kchunk, ks == 0, Ws);
}

// ---------------- K_gates v2 (fast): k6-style MFMA streaming GEMM ----------------
// y=0: gi K[0,1280); y=1: gi K[1280,2560); y=2: gh K[0,1024). Grid (48, 3).
__global__ __launch_bounds__(256) void k_gates_mfma(
    const unsigned short* __restrict__ rb, const unsigned short* __restrict__ hb,
    const float* __restrict__ Wih, const float* __restrict__ Whh,
    const float* __restrict__ bih, const float* __restrict__ bhh,
    float* __restrict__ gi, float* __restrict__ gh) {
  __shared__ __align__(16) float Ws[64 * 128];
  __shared__ __align__(16) unsigned short Xs[64 * 128];
  int tid = threadIdx.x;
  int wv = tid >> 6, lane = tid & 63;
  int r = lane & 15, kg = lane >> 4;
  int n0 = blockIdx.x * 64;
  int n = n0 + wv * 16 + r;
  int s = blockIdx.y;
  const float* W; const unsigned short* x; const float* bias;
  float* po; int lda, kbase, KC; bool addb;
  if (s < 2) { W = Wih; x = rb; lda = EC; kbase = s * 1280; KC = 1280;
               po = gi + (size_t)s * B_ * H3; bias = bih; addb = (s == 0); }
  else       { W = Whh; x = hb; lda = H_; kbase = 0; KC = 1024;
               po = gh; bias = bhh; addb = true; }
  f32x4 a0 = {0.f, 0.f, 0.f, 0.f}, a1 = a0, a2 = a0, a3 = a0;

  for (int ch = 0; ch < KC; ch += 128) {
    __syncthreads();
    #pragma unroll
    for (int i = 0; i < 8; ++i) {
      int rowW = (wv * 8 + i) * 2 + (lane >> 5);
      int sc = (lane & 31) ^ (rowW & 15);
      gload16(&W[(size_t)(n0 + rowW) * lda + kbase + ch + sc * 4],
              &Ws[(wv * 8 + i) * 256]);
    }
    #pragma unroll
    for (int i = 0; i < 4; ++i) {
      int rowX = (wv * 4 + i) * 4 + (lane >> 4);
      int sc = (lane & 15) ^ (rowX & 15);
      gload16(&x[(size_t)rowX * lda + kbase + ch + sc * 8],
              &Xs[(wv * 4 + i) * 512]);
    }
    __syncthreads();
    #pragma unroll
    for (int ss = 0; ss < 4; ++ss) {
      int uw0 = (ss * 8 + kg * 2) ^ r;
      int uw1 = (ss * 8 + kg * 2 + 1) ^ r;
      int rw = wv * 16 + r;
      float4 wa = *(const float4*)&Ws[rw * 128 + uw0 * 4];
      float4 wb = *(const float4*)&Ws[rw * 128 + uw1 * 4];
      u16x8 bu;
      bu[0] = f2bf(wa.x); bu[1] = f2bf(wa.y); bu[2] = f2bf(wa.z); bu[3] = f2bf(wa.w);
      bu[4] = f2bf(wb.x); bu[5] = f2bf(wb.y); bu[6] = f2bf(wb.z); bu[7] = f2bf(wb.w);
      bf16x8 bf = __builtin_bit_cast(bf16x8, bu);
      int ux = (ss * 4 + kg) ^ r;
      u16x8 x0 = *(const u16x8*)&Xs[(r)      * 128 + ux * 8];
      u16x8 x1 = *(const u16x8*)&Xs[(16 + r) * 128 + ux * 8];
      u16x8 x2 = *(const u16x8*)&Xs[(32 + r) * 128 + ux * 8];
      u16x8 x3 = *(const u16x8*)&Xs[(48 + r) * 128 + ux * 8];
      a0 = __builtin_amdgcn_mfma_f32_16x16x32_bf16(__builtin_bit_cast(bf16x8, x0), bf, a0, 0, 0, 0);
      a1 = __builtin_amdgcn_mfma_f32_16x16x32_bf16(__builtin_bit_cast(bf16x8, x1), bf, a1, 0, 0, 0);
      a2 = __builtin_amdgcn_mfma_f32_16x16x32_bf16(__builtin_bit_cast(bf16x8, x2), bf, a2, 0, 0, 0);
      a3 = __builtin_amdgcn_mfma_f32_16x16x32_bf16(__builtin_bit_cast(bf16x8, x3), bf, a3, 0, 0, 0);
    }
  }
  float bv = addb ? bias[n] : 0.f;
  int r0 = kg * 4;
  #pragma unroll
  for (int rr = 0; rr < 4; ++rr) {
    po[(size_t)(r0 + rr) * H3 + n]      = a0[rr] + bv;
    po[(size_t)(16 + r0 + rr) * H3 + n] = a1[rr] + bv;
    po[(size_t)(32 + r0 + rr) * H3 + n] = a2[rr] + bv;
    po[(size_t)(48 + r0 + rr) * H3 + n] = a3[rr] + bv;
  }
}

// ---------------- K5c: GRU gates; writes hnew + xb[:H_] ----------------
__global__ void k5c_gates(const float* __restrict__ gip, const float* __restrict__ ghp,
                          int gis, int ghs, int do_ctx,
                          const float* __restrict__ hidden, const float* __restrict__ context,
                          float* __restrict__ hnew_out, unsigned short* __restrict__ xb) {
  int b = blockIdx.x;
  for (int h = threadIdx.x; h < H_; h += blockDim.x) {
    float ir = 0.f, iz = 0.f, inn = 0.f;
    for (int s = 0; s < gis; ++s) {
      const float* gb = gip + (size_t)s * B_ * H3 + (size_t)b * H3;
      ir += gb[h]; iz += gb[H_ + h]; inn += gb[H2 + h];
    }
    float hr = 0.f, hz = 0.f, hn = 0.f;
    for (int s = 0; s < ghs; ++s) {
      const float* gb = ghp + (size_t)s * B_ * H3 + (size_t)b * H3;
      hr += gb[h]; hz += gb[H_ + h]; hn += gb[H2 + h];
    }
    float r = 1.f / (1.f + expf(-(ir + hr)));
    float z = 1.f / (1.f + expf(-(iz + hz)));
    float n = tanhf(inn + r * hn);
    float hv = hidden[b * H_ + h];
    float hnew = (1.f - z) * n + z * hv;
    hnew_out[b * H_ + h] = hnew;
    xb[b * H3 + h] = f2bf(hnew);
  }
  if (do_ctx)
    for (int c = threadIdx.x; c < H2; c += blockDim.x)
      xb[b * H3 + H_ + c] = f2bf(context[b * H2 + c]);
}

// ---------------- k6 helper (slow path) ----------------
__device__ __forceinline__ void k6_stage(float4 wa, float4 wb,
    const unsigned short* __restrict__ xp, int off,
    f32x4& a0, f32x4& a1, f32x4& a2, f32x4& a3) {
  u16x8 bu;
  bu[0] = f2bf(wa.x); bu[1] = f2bf(wa.y); bu[2] = f2bf(wa.z); bu[3] = f2bf(wa.w);
  bu[4] = f2bf(wb.x); bu[5] = f2bf(wb.y); bu[6] = f2bf(wb.z); bu[7] = f2bf(wb.w);
  bf16x8 bf = __builtin_bit_cast(bf16x8, bu);
  u16x8 x0 = *(const u16x8*)(xp + off);
  u16x8 x1 = *(const u16x8*)(xp + 16 * H3 + off);
  u16x8 x2 = *(const u16x8*)(xp + 32 * H3 + off);
  u16x8 x3 = *(const u16x8*)(xp + 48 * H3 + off);
  a0 = __builtin_amdgcn_mfma_f32_16x16x32_bf16(__builtin_bit_cast(bf16x8, x0), bf, a0, 0, 0, 0);
  a1 = __builtin_amdgcn_mfma_f32_16x16x32_bf16(__builtin_bit_cast(bf16x8, x1), bf, a1, 0, 0, 0);
  a2 = __builtin_amdgcn_mfma_f32_16x16x32_bf16(__builtin_bit_cast(bf16x8, x2), bf, a2, 0, 0, 0);
  a3 = __builtin_amdgcn_mfma_f32_16x16x32_bf16(__builtin_bit_cast(bf16x8, x3), bf, a3, 0, 0, 0);
}

// ---------------- K6 v5 (fast) ----------------
__global__ __launch_bounds__(256) void k6_split(
    const unsigned short* __restrict__ xb, const float* __restrict__ W,
    float* __restrict__ part) {
  __shared__ __align__(16) float Ws[64 * 128];
  __shared__ __align__(16) unsigned short Xs[64 * 128];
  int tid = threadIdx.x;
  int wv = tid >> 6, lane = tid & 63;
  int r = lane & 15, kg = lane >> 4;
  int n = blockIdx.x * 64 + wv * 16 + r;
  int ks = blockIdx.y;
  const int KC = H3 / NS;                   // 768
  int kbase = ks * KC;
  f32x4 a0 = {0.f, 0.f, 0.f, 0.f}, a1 = a0, a2 = a0, a3 = a0;

  for (int ch = 0; ch < KC; ch += 128) {
    __syncthreads();
    #pragma unroll
    for (int i = 0; i < 8; ++i) {
      int rowW = (wv * 8 + i) * 2 + (lane >> 5);
      int sc = (lane & 31) ^ (rowW & 15);
      gload16(&W[(size_t)(blockIdx.x * 64 + rowW) * H3 + kbase + ch + sc * 4],
              &Ws[(wv * 8 + i) * 256]);
    }
    #pragma unroll
    for (int i = 0; i < 4; ++i) {
      int rowX = (wv * 4 + i) * 4 + (lane >> 4);
      int sc = (lane & 15) ^ (rowX & 15);
      gload16(&xb[(size_t)rowX * H3 + kbase + ch + sc * 8],
              &Xs[(wv * 4 + i) * 512]);
    }
    __syncthreads();
    #pragma unroll
    for (int s = 0; s < 4; ++s) {
      int uw0 = (s * 8 + kg * 2) ^ r;
      int uw1 = (s * 8 + kg * 2 + 1) ^ r;
      int rw = wv * 16 + r;
      float4 wa = *(const float4*)&Ws[rw * 128 + uw0 * 4];
      float4 wb = *(const float4*)&Ws[rw * 128 + uw1 * 4];
      u16x8 bu;
      bu[0] = f2bf(wa.x); bu[1] = f2bf(wa.y); bu[2] = f2bf(wa.z); bu[3] = f2bf(wa.w);
      bu[4] = f2bf(wb.x); bu[5] = f2bf(wb.y); bu[6] = f2bf(wb.z); bu[7] = f2bf(wb.w);
      bf16x8 bf = __builtin_bit_cast(bf16x8, bu);
      int ux = (s * 4 + kg) ^ r;
      u16x8 x0 = *(const u16x8*)&Xs[(r)      * 128 + ux * 8];
      u16x8 x1 = *(const u16x8*)&Xs[(16 + r) * 128 + ux * 8];
      u16x8 x2 = *(const u16x8*)&Xs[(32 + r) * 128 + ux * 8];
      u16x8 x3 = *(const u16x8*)&Xs[(48 + r) * 128 + ux * 8];
      a0 = __builtin_amdgcn_mfma_f32_16x16x32_bf16(__builtin_bit_cast(bf16x8, x0), bf, a0, 0, 0, 0);
      a1 = __builtin_amdgcn_mfma_f32_16x16x32_bf16(__builtin_bit_cast(bf16x8, x1), bf, a1, 0, 0, 0);
      a2 = __builtin_amdgcn_mfma_f32_16x16x32_bf16(__builtin_bit_cast(bf16x8, x2), bf, a2, 0, 0, 0);
      a3 = __builtin_amdgcn_mfma_f32_16x16x32_bf16(__builtin_bit_cast(bf16x8, x3), bf, a3, 0, 0, 0);
    }
  }
  float* po = part + (size_t)ks * B_ * KY;
  int r0 = kg * 4;
  #pragma unroll
  for (int rr = 0; rr < 4; ++rr) {
    po[(size_t)(r0 + rr) * KY + n]      = a0[rr];
    po[(size_t)(16 + r0 + rr) * KY + n] = a1[rr];
    po[(size_t)(32 + r0 + rr) * KY + n] = a2[rr];
    po[(size_t)(48 + r0 + rr) * KY + n] = a3[rr];
  }
}

// ---------------- K6 legacy (slow path) ----------------
__global__ __launch_bounds__(256) void k6_lsm_mfma(
    const unsigned short* __restrict__ xb, const float* __restrict__ W,
    const float* __restrict__ bias, float* __restrict__ out) {
  int tid = threadIdx.x;
  int wv = tid >> 6, lane = tid & 63;
  int n = blockIdx.x * 64 + wv * 16 + (lane & 15);
  int kg = lane >> 4;
  const float* wp = W + (size_t)n * H3 + kg * 8;
  const unsigned short* xp = xb + (size_t)(lane & 15) * H3 + kg * 8;
  f32x4 a0 = {0.f, 0.f, 0.f, 0.f}, a1 = a0, a2 = a0, a3 = a0;
  for (int k0 = 0; k0 < H3; k0 += 128) {
    float4 wA0 = *(const float4*)(wp + k0 +   0);
    float4 wB0 = *(const float4*)(wp + k0 +   4);
    float4 wA1 = *(const float4*)(wp + k0 +  32);
    float4 wB1 = *(const float4*)(wp + k0 +  36);
    float4 wA2 = *(const float4*)(wp + k0 +  64);
    float4 wB2 = *(const float4*)(wp + k0 +  68);
    float4 wA3 = *(const float4*)(wp + k0 +  96);
    float4 wB3 = *(const float4*)(wp + k0 + 100);
    k6_stage(wA0, wB0, xp, k0 +  0, a0, a1, a2, a3);
    k6_stage(wA1, wB1, xp, k0 + 32, a0, a1, a2, a3);
    k6_stage(wA2, wB2, xp, k0 + 64, a0, a1, a2, a3);
    k6_stage(wA3, wB3, xp, k0 + 96, a0, a1, a2, a3);
  }
  float bv = bias[n];
  int r0 = kg * 4;
  #pragma unroll
  for (int r = 0; r < 4; ++r) {
    out[(size_t)(r0 + r) * KY + n]      = a0[r] + bv;
    out[(size_t)(16 + r0 + r) * KY + n] = a1[r] + bv;
    out[(size_t)(32 + r0 + r) * KY + n] = a2[r] + bv;
    out[(size_t)(48 + r0 + r) * KY + n] = a3[r] + bv;
  }
}

// ---------------- K7a ----------------
__global__ __launch_bounds__(256) void k7a(const float* __restrict__ part,
                                           const float* __restrict__ bias,
                                           float* __restrict__ out,
                                           float* __restrict__ pm, float* __restrict__ ps) {
  int b = blockIdx.y, q = blockIdx.x;
  float* orow = out + (size_t)b * KY;
  int base = q * (KY / 4);
  int end  = base + (KY / 4);
  float mx = -1e30f;
  for (int k = base + threadIdx.x; k < end; k += 256) {
    float v = bias[k];
    #pragma unroll
    for (int s = 0; s < NS; ++s)
      v += part[(size_t)s * B_ * KY + (size_t)b * KY + k];
    orow[k] = v;
    mx = fmaxf(mx, v);
  }
  __shared__ float sm[256];
  sm[threadIdx.x] = mx; __syncthreads();
  for (int off = 128; off; off >>= 1) {
    if (threadIdx.x < off) sm[threadIdx.x] = fmaxf(sm[threadIdx.x], sm[threadIdx.x + off]);
    __syncthreads();
  }
  float M = sm[0]; __syncthreads();
  float s = 0.f;
  for (int k = base + threadIdx.x; k < end; k += 256)
    s += expf(orow[k] - M);
  sm[threadIdx.x] = s; __syncthreads();
  for (int off = 128; off; off >>= 1) {
    if (threadIdx.x < off) sm[threadIdx.x] += sm[threadIdx.x + off];
    __syncthreads();
  }
  if (threadIdx.x == 0) { pm[b * 4 + q] = M; ps[b * 4 + q] = sm[0]; }
}

// ---------------- K8f ----------------
__global__ void k8f_out(float* __restrict__ outp, const float* __restrict__ pm,
                        const float* __restrict__ ps) {
  int b = blockIdx.y;
  float m0 = pm[b*4], m1 = pm[b*4+1], m2 = pm[b*4+2], m3 = pm[b*4+3];
  float M = fmaxf(fmaxf(m0, m1), fmaxf(m2, m3));
  float s = ps[b*4]   * expf(m0 - M) + ps[b*4+1] * expf(m1 - M)
          + ps[b*4+2] * expf(m2 - M) + ps[b*4+3] * expf(m3 - M);
  float lse = M + logf(s);
  int k = blockIdx.x * 256 + threadIdx.x;
  size_t idx = (size_t)b * KY + k;
  outp[idx] = outp[idx] - lse;
}

// ---------------- slow-path K7/K8 ----------------
__global__ void k7_lse(const float* __restrict__ logits, float* __restrict__ lse) {
  int b = blockIdx.x;
  const float* row = logits + (size_t)b * KY;
  __shared__ float sm[256];
  float mx = -1e30f;
  for (int k = threadIdx.x; k < KY; k += 256) mx = fmaxf(mx, row[k]);
  sm[threadIdx.x] = mx; __syncthreads();
  for (int off = 128; off; off >>= 1) {
    if (threadIdx.x < off) sm[threadIdx.x] = fmaxf(sm[threadIdx.x], sm[threadIdx.x + off]);
    __syncthreads();
  }
  mx = sm[0]; __syncthreads();
  float s = 0.f;
  for (int k = threadIdx.x; k < KY; k += 256) s += expf(row[k] - mx);
  sm[threadIdx.x] = s; __syncthreads();
  for (int off = 128; off; off >>= 1) {
    if (threadIdx.x < off) sm[threadIdx.x] += sm[threadIdx.x + off];
    __syncthreads();
  }
  if (threadIdx.x == 0) lse[b] = mx + logf(sm[0]);
}
__global__ void k8_out(float* __restrict__ outp, const float* __restrict__ lse) {
  int b = blockIdx.y;
  int k = blockIdx.x * 256 + threadIdx.x;
  size_t idx = (size_t)b * KY + k;
  outp[idx] = outp[idx] - lse[b];
}

extern "C" void kernel_launch(void* const* d_in, const int* in_sizes, int n_in,
                              void* d_out, int out_size, void* d_ws, size_t ws_size,
                              hipStream_t stream) {
  const int*   input  = (const int*)  d_in[0];
  const float* hidden = (const float*)d_in[1];
  const float* enc    = (const float*)d_in[2];
  const float* emb_W  = (const float*)d_in[3];
  const float* Wih    = (const float*)d_in[4];
  const float* Whh    = (const float*)d_in[5];
  const float* bih    = (const float*)d_in[6];
  const float* bhh    = (const float*)d_in[7];
  const float* lsm_W  = (const float*)d_in[8];
  const float* lsm_b  = (const float*)d_in[9];
  const float* aW1    = (const float*)d_in[10];
  const float* ab1    = (const float*)d_in[11];
  const float* aW2    = (const float*)d_in[12];
  const float* ab2    = (const float*)d_in[13];

  float* out   = (float*)d_out;
  float* hnew  = out + (size_t)B_ * KY;

  int gis = 5, ghs = 2;   // layout sizing (fast path uses 2/1 within this space)
  size_t base_fast = 65536 + 131072 + 8192 + 131072 + 163840
                   + (size_t)gis * 196608 + (size_t)ghs * 196608
                   + 98304 + 64 + 256 + 256 + (size_t)NS * B_ * KY;
  size_t need_fast = (base_fast + 8388608 + 1048576) * 4;
  int fast = (ws_size >= need_fast);
  if (!fast) {
    size_t base_slow = 65536 + 131072 + 8192 + 131072 + 163840
                     + (size_t)gis * 196608 + (size_t)ghs * 196608 + 98304 + 64;
    if (ws_size < base_slow * 4) { gis = 1; ghs = 1; }
  }

  float* ws = (float*)d_ws;
  unsigned short* encb = (unsigned short*)ws;
  unsigned short* w1b  = encb + (fast ? 16777216 : 0);
  float* fbase = fast ? (float*)(w1b + 2097152) : ws;
  float* hpart     = fbase;
  float* scorepart = hpart + 65536;
  float* w         = scorepart + 131072;
  float* context   = w + 8192;
  float* rnn_in    = context + 131072;            // slow path f32; fast path carves rb/hb here
  unsigned short* rb = (unsigned short*)rnn_in;   // 64*2560 bf16
  unsigned short* hb = rb + 163840;               // 64*1024 bf16 (within rnn_in's 655KB)
  float* gi        = rnn_in + 163840;
  float* gh        = gi + (size_t)gis * 196608;
  unsigned short* xb = (unsigned short*)(gh + (size_t)ghs * 196608);
  float* lse       = (float*)(xb + 196608);
  float* pm        = lse + 64;
  float* ps        = pm + 256;
  float* part      = ps + 256;            // NS*64*32000 f32 (fast only)

  k1_hpart<<<dim3(256, 64), 256, 0, stream>>>(hidden, aW1, ab1, hpart);
  if (fast) {
    kc_all<<<9248, 256, 0, stream>>>(enc, aW1, hidden, encb, w1b, hb);
    k2_mfma<<<512, 256, 0, stream>>>(encb, w1b, hpart, aW2, scorepart);
    k4c_ctx<<<dim3(5, B_), 256, 0, stream>>>(encb, scorepart, ab2, input, emb_W, rb, xb);
    k_gates_mfma<<<dim3(48, 3), 256, 0, stream>>>(rb, hb, Wih, Whh, bih, bhh, gi, gh);
    k5c_gates<<<B_, 256, 0, stream>>>(gi, gh, 2, 1, 0, hidden, context, hnew, xb);
    k6_split<<<dim3(KY / 64, NS), 256, 0, stream>>>(xb, lsm_W, part);
    k7a<<<dim3(4, B_), 256, 0, stream>>>(part, lsm_b, out, pm, ps);
    k8f_out<<<dim3(KY / 256, B_), 256, 0, stream>>>(out, pm, ps);
  } else {
    k2_gemm_score<<<dim3(M_ / 64, 16), 256, 0, stream>>>(enc, aW1, hpart, aW2, scorepart);
    k3_softmax<<<B_, TX, 0, stream>>>(scorepart, ab2, w, 16);
    k4_context<<<dim3(H2 / 256, B_), 256, 0, stream>>>(enc, w, context);
    k5a_rnnin<<<B_, 256, 0, stream>>>(input, emb_W, context, rnn_in);
    k_gemm_T<<<dim3(H3 / 64, gis), 256, 0, stream>>>(rnn_in, Wih, bih, gi, H3, EC);
    k_gemm_T<<<dim3(H3 / 64, ghs), 256, 0, stream>>>(hidden, Whh, bhh, gh, H3, H_);
    k5c_gates<<<B_, 256, 0, stream>>>(gi, gh, gis, ghs, 1, hidden, context, hnew, xb);
    k6_lsm_mfma<<<KY / 64, 256, 0, stream>>>(xb, lsm_W, lsm_b, out);
    k7_lse<<<B_, 256, 0, stream>>>(out, lse);
    k8_out<<<dim3(KY / 256, B_), 256, 0, stream>>>(out, lse);
  }
}